// Round 6
// baseline (3560.661 us; speedup 1.0000x reference)
//
#include <hip/hip_runtime.h>

#define B_ 64
#define S_ 1024
#define I_ 512
#define H_ 512
#define SH_ (S_ * H_)
#define OUT_H (B_ * SH_)
#define BH_ (B_ * H_)

// ---------------------------------------------------------------------------
// Kernel 1: x_proj GEMM.  out[m,n] = sum_k A[m,k]*W[n,k] + bih[n] + bhh[n]
// (unchanged)
// ---------------------------------------------------------------------------
__global__ __launch_bounds__(256) void xproj_kernel(
    const float* __restrict__ A, const float* __restrict__ W,
    const float* __restrict__ bih, const float* __restrict__ bhh,
    float* __restrict__ out)
{
  __shared__ float As[16][132];
  __shared__ float Bs[16][132];
  const int tid = threadIdx.x;
  const int m0 = blockIdx.x * 128;
  const int n0 = blockIdx.y * 128;

  float acc[8][8];
  #pragma unroll
  for (int i = 0; i < 8; ++i)
    #pragma unroll
    for (int j = 0; j < 8; ++j) acc[i][j] = 0.f;

  const int mb = (tid >> 4) * 8;
  const int nb = (tid & 15) * 8;

  for (int kb = 0; kb < I_ / 16; ++kb) {
    const int k0 = kb * 16;
    __syncthreads();
    #pragma unroll
    for (int l = 0; l < 2; ++l) {
      int s  = tid + l * 256;
      int ml = s >> 2;
      int kc = s & 3;
      float4 av = *(const float4*)(A + (size_t)(m0 + ml) * I_ + k0 + kc * 4);
      As[kc*4+0][ml] = av.x; As[kc*4+1][ml] = av.y;
      As[kc*4+2][ml] = av.z; As[kc*4+3][ml] = av.w;
      float4 bv = *(const float4*)(W + (size_t)(n0 + ml) * I_ + k0 + kc * 4);
      Bs[kc*4+0][ml] = bv.x; Bs[kc*4+1][ml] = bv.y;
      Bs[kc*4+2][ml] = bv.z; Bs[kc*4+3][ml] = bv.w;
    }
    __syncthreads();
    #pragma unroll
    for (int k = 0; k < 16; ++k) {
      float4 a0 = *(const float4*)&As[k][mb];
      float4 a1 = *(const float4*)&As[k][mb + 4];
      float4 b0 = *(const float4*)&Bs[k][nb];
      float4 b1 = *(const float4*)&Bs[k][nb + 4];
      float a[8] = {a0.x,a0.y,a0.z,a0.w,a1.x,a1.y,a1.z,a1.w};
      float b[8] = {b0.x,b0.y,b0.z,b0.w,b1.x,b1.y,b1.z,b1.w};
      #pragma unroll
      for (int i = 0; i < 8; ++i)
        #pragma unroll
        for (int j = 0; j < 8; ++j) acc[i][j] += a[i] * b[j];
    }
  }

  float bias[8];
  #pragma unroll
  for (int j = 0; j < 8; ++j) bias[j] = bih[n0 + nb + j] + bhh[n0 + nb + j];
  #pragma unroll
  for (int i = 0; i < 8; ++i) {
    float4 v0 = make_float4(acc[i][0]+bias[0], acc[i][1]+bias[1],
                            acc[i][2]+bias[2], acc[i][3]+bias[3]);
    float4 v1 = make_float4(acc[i][4]+bias[4], acc[i][5]+bias[5],
                            acc[i][6]+bias[6], acc[i][7]+bias[7]);
    float* o = out + (size_t)(m0 + mb + i) * H_ + n0 + nb;
    *(float4*)o       = v0;
    *(float4*)(o + 4) = v1;
  }
}

// ---------------------------------------------------------------------------
// Kernel 2: init — zero tag-slot 0.  (d_ws re-poisoned to 0xAA per launch.)
// Slot0's first tagged write (h_2) carries tag 1; poison bit31=1 would alias
// it, so slot0 must be cleared.  Slot1's poison (bit31=1) differs from the
// expected tag 0 at t=1, so it needs no init.  h0 read from d_in at t=0.
// ---------------------------------------------------------------------------
__global__ __launch_bounds__(256) void init_kernel(unsigned* __restrict__ hbu)
{
  int i = blockIdx.x * 256 + threadIdx.x;
  if (i < BH_) hbu[i] = 0u;
}

// ---------------------------------------------------------------------------
// DPP wave-row reduction (VALU pipe).  Field-proven numerically in the R3
// bench run (passed, absmax 0.0078).  After xor1, xor2, half-row mirror,
// row mirror: every lane of each 16-lane row holds that row's sum.
// ---------------------------------------------------------------------------
template <int CTRL>
__device__ __forceinline__ float dpp_add(float x) {
  return x + __int_as_float(__builtin_amdgcn_update_dpp(
      0, __float_as_int(x), CTRL, 0xF, 0xF, true));
}
__device__ __forceinline__ float rowsum16(float x) {
  x = dpp_add<0xB1>(x);    // quad_perm [1,0,3,2]  : xor1
  x = dpp_add<0x4E>(x);    // quad_perm [2,3,0,1]  : xor2
  x = dpp_add<0x141>(x);   // row_half_mirror      : xor4-equiv
  x = dpp_add<0x140>(x);   // row_mirror           : xor8-equiv
  return x;
}

#define FMA4(A, W4, s) \
  A.x += W4.x * (s); A.y += W4.y * (s); A.z += W4.z * (s); A.w += W4.w * (s)

// W panel load: column 64*J + lane of 16 rows, as 4 float4 groups (named SSA).
#define LDW(J) \
  float4 W##J##A = make_float4(p0[64*J],  p1[64*J],  p2[64*J],  p3[64*J]);  \
  float4 W##J##B = make_float4(p4[64*J],  p5[64*J],  p6[64*J],  p7[64*J]);  \
  float4 W##J##C = make_float4(p8[64*J],  p9[64*J],  p10[64*J], p11[64*J]); \
  float4 W##J##D = make_float4(p12[64*J], p13[64*J], p14[64*J], p15[64*J]);

#define FMAJ(J, HV) \
  FMA4(aA, W##J##A, HV); FMA4(aB, W##J##B, HV); \
  FMA4(aC, W##J##C, HV); FMA4(aD, W##J##D, HV);

#define AL(P) __hip_atomic_load((P), __ATOMIC_RELAXED, __HIP_MEMORY_SCOPE_AGENT)

// ---------------------------------------------------------------------------
// Kernel 3: recurrence — R10: FULLY WAVE-AUTONOMOUS.
// R4/R8/R9 post-mortem: three different sync skeletons, all ~1680 us -> the
// invariant cost is the shared stage->barrier->fan-in->handoff chain: ~80
// LDS wave-ops/CU/step (b128 ~12-16cy each) + a 2-wave serial LDS reduce
// behind a barrier, chained with the L2 RTT instead of overlapped.
// R10: 2048 waves == 2048 (batch, 16-output-slice) units.  Wave (b,s) owns
// batch b, outputs [16s,16s+16), FULL K=512:
//   * lane L spin-loads h[b][64j+L] (j=0..7) -- 8 tagged dwords, coalesced;
//     FMA runs straight from the spin registers: NO LDS h-staging;
//   * W cols {64j+L} x 16 rows = 128 floats/lane in 32 NAMED float4 SSA
//     (R8-proven residency recipe + waves_per_eu(2,2); VGPR ~190 < 256);
//   * k-reduce: rowsum16 DPP x16 (VALU), then ONE 64-dword LDS transpose
//     (1 write + 1 b128 read per wave) -> lanes 0..15 hold the 4 row-sums;
//   * lanes 0..15 finalize EVERY step (wave is its own producer; no
//     rotation, no barrier, no cross-wave fan-in);
//   * xp prefetched one full step ahead (issued after the tagged store,
//     consumed after next spin+FMA ~1000cy -> HBM latency hidden).
// Locality: batch b's 32 waves = WGs {x+8m : m=4(b&7)..4(b&7)+3}, x=b>>3,
// all == x (mod 8) -> one XCD for the whole handshake.
// Safety (wave-granular induction, protocol byte-identical): wave stores
// h_{t+1} only after detecting ALL of h_t => every wave of batch b stored
// h_t => each had consumed h_{t-1} (data-dep before its store) => slot
// (t+1)&1 overwrite of h_{t-1} is safe.  Ternary ReLU + bit31 mask kept.
// ---------------------------------------------------------------------------
__global__ __launch_bounds__(512)
__attribute__((amdgpu_waves_per_eu(2, 2)))
void recur_kernel(
    const float* __restrict__ Whh, const float* __restrict__ h0,
    float* __restrict__ out, unsigned* __restrict__ hbu)
{
  const int tid  = threadIdx.x;
  const int lane = tid & 63;
  const int w    = tid >> 6;           // wave id 0..7
  const int g    = blockIdx.x;
  const int x    = g & 7;              // XCD slot
  const int m    = g >> 3;             // 0..31
  const int b    = x * 8 + (m >> 2);   // batch 0..63
  const int s    = (m & 3) * 8 + w;    // output slice 0..31
  const int os   = s * 16;             // outputs [os, os+16)

  __shared__ float redw[8][64];        // per-wave transpose scratch (2 KB)

  // ---- W panel: rows os..os+15, cols {64j+lane} -> 32 named float4 ----
  const float* pr  = Whh + (size_t)os * H_ + lane;
  const float* p0  = pr;           const float* p1  = pr +  1 * H_;
  const float* p2  = pr +  2 * H_; const float* p3  = pr +  3 * H_;
  const float* p4  = pr +  4 * H_; const float* p5  = pr +  5 * H_;
  const float* p6  = pr +  6 * H_; const float* p7  = pr +  7 * H_;
  const float* p8  = pr +  8 * H_; const float* p9  = pr +  9 * H_;
  const float* p10 = pr + 10 * H_; const float* p11 = pr + 11 * H_;
  const float* p12 = pr + 12 * H_; const float* p13 = pr + 13 * H_;
  const float* p14 = pr + 14 * H_; const float* p15 = pr + 15 * H_;
  LDW(0) LDW(1) LDW(2) LDW(3) LDW(4) LDW(5) LDW(6) LDW(7)

  // finalist lanes 0..15: output o = os + lane of batch b
  float* outp   = out + (size_t)b * SH_ + os + lane;    // advances by H_/step
  unsigned* hdb = hbu + (size_t)b * H_ + os + lane;     // + slot*BH_

  float xpn = 0.f;
  if (lane < 16) xpn = *outp;          // xp(t=0) prologue prefetch

  const int a   = lane & 15;           // transpose slot
  const int rr  = lane >> 4;           // k-row 0..3

  for (int t = 0; t < S_; ++t) {
    const float xp = xpn;

    // ---- spin-load this lane's 8 h values (tagged, coalesced) ----
    float hv0, hv1, hv2, hv3, hv4, hv5, hv6, hv7;
    if (t == 0) {
      const float* hp = h0 + (size_t)b * H_ + lane;
      hv0 = hp[0];   hv1 = hp[64];  hv2 = hp[128]; hv3 = hp[192];
      hv4 = hp[256]; hv5 = hp[320]; hv6 = hp[384]; hv7 = hp[448];
    } else {
      const unsigned* hs = hbu + (t & 1) * BH_ + (size_t)b * H_ + lane;
      const unsigned expct = ((unsigned)t >> 1) & 1u;
      unsigned u0 = AL(hs +   0), u1 = AL(hs +  64);
      unsigned u2 = AL(hs + 128), u3 = AL(hs + 192);
      unsigned u4 = AL(hs + 256), u5 = AL(hs + 320);
      unsigned u6 = AL(hs + 384), u7 = AL(hs + 448);
      while ((u0 >> 31) != expct) u0 = AL(hs +   0);
      while ((u1 >> 31) != expct) u1 = AL(hs +  64);
      while ((u2 >> 31) != expct) u2 = AL(hs + 128);
      while ((u3 >> 31) != expct) u3 = AL(hs + 192);
      while ((u4 >> 31) != expct) u4 = AL(hs + 256);
      while ((u5 >> 31) != expct) u5 = AL(hs + 320);
      while ((u6 >> 31) != expct) u6 = AL(hs + 384);
      while ((u7 >> 31) != expct) u7 = AL(hs + 448);
      hv0 = __uint_as_float(u0 & 0x7fffffffu);
      hv1 = __uint_as_float(u1 & 0x7fffffffu);
      hv2 = __uint_as_float(u2 & 0x7fffffffu);
      hv3 = __uint_as_float(u3 & 0x7fffffffu);
      hv4 = __uint_as_float(u4 & 0x7fffffffu);
      hv5 = __uint_as_float(u5 & 0x7fffffffu);
      hv6 = __uint_as_float(u6 & 0x7fffffffu);
      hv7 = __uint_as_float(u7 & 0x7fffffffu);
    }

    // ---- 128 FMA/lane: 16 outputs x 8 k, straight from spin regs ----
    float4 aA = make_float4(0.f, 0.f, 0.f, 0.f);
    float4 aB = make_float4(0.f, 0.f, 0.f, 0.f);
    float4 aC = make_float4(0.f, 0.f, 0.f, 0.f);
    float4 aD = make_float4(0.f, 0.f, 0.f, 0.f);
    FMAJ(0, hv0) FMAJ(1, hv1) FMAJ(2, hv2) FMAJ(3, hv3)
    FMAJ(4, hv4) FMAJ(5, hv5) FMAJ(6, hv6) FMAJ(7, hv7)

    // ---- k-reduce: 16 DPP row-sums (each 16-lane row = one k-quarter) ----
    aA.x = rowsum16(aA.x); aA.y = rowsum16(aA.y);
    aA.z = rowsum16(aA.z); aA.w = rowsum16(aA.w);
    aB.x = rowsum16(aB.x); aB.y = rowsum16(aB.y);
    aB.z = rowsum16(aB.z); aB.w = rowsum16(aB.w);
    aC.x = rowsum16(aC.x); aC.y = rowsum16(aC.y);
    aC.z = rowsum16(aC.z); aC.w = rowsum16(aC.w);
    aD.x = rowsum16(aD.x); aD.y = rowsum16(aD.y);
    aD.z = rowsum16(aD.z); aD.w = rowsum16(aD.w);

    // ---- transpose via LDS: lane (rr, a) contributes acc #a's row-rr sum
    float4 gsel = (a >> 2) == 0 ? aA : (a >> 2) == 1 ? aB
                : (a >> 2) == 2 ? aC : aD;
    float sel   = (a & 3) == 0 ? gsel.x : (a & 3) == 1 ? gsel.y
                : (a & 3) == 2 ? gsel.z : gsel.w;
    redw[w][a * 4 + rr] = sel;
    asm volatile("s_waitcnt lgkmcnt(0)" ::: "memory");  // same-wave wr->rd
    __builtin_amdgcn_sched_barrier(0);

    // ---- finalize: lanes 0..15, output os+lane, EVERY step ----
    if (lane < 16) {
      float4 rv = *(const float4*)&redw[w][lane * 4];
      float pre = xp + ((rv.x + rv.y) + (rv.z + rv.w));
      float v = pre > 0.f ? pre : 0.f;          // ternary: never -0.0
      const unsigned tg = ((((unsigned)(t + 1)) >> 1) & 1u) << 31;
      __hip_atomic_store(hdb + ((t + 1) & 1) * BH_,
                         (__float_as_uint(v) & 0x7fffffffu) | tg,
                         __ATOMIC_RELAXED, __HIP_MEMORY_SCOPE_AGENT);
      *outp = v;                                 // out[b,t,:] = h_{t+1}
      if (t == S_ - 1)
        out[(size_t)OUT_H + (size_t)b * H_ + os + lane] = v;  // h_final
      outp += H_;
      if (t + 1 < S_) xpn = *outp;   // prefetch next step's xp (1 step deep)
    }
    // No barriers anywhere: the wave is its own producer; peers couple only
    // through the tagged h slots (the spin is the synchronization point).
  }
}

// ---------------------------------------------------------------------------
extern "C" void kernel_launch(void* const* d_in, const int* in_sizes, int n_in,
                              void* d_out, int out_size, void* d_ws, size_t ws_size,
                              hipStream_t stream)
{
  const float* inputs = (const float*)d_in[0];  // [B,S,I]
  const float* h0     = (const float*)d_in[1];  // [1,B,H]
  const float* w_ih   = (const float*)d_in[2];  // [H,I]
  const float* w_hh   = (const float*)d_in[3];  // [H,H]
  const float* b_ih   = (const float*)d_in[4];  // [H]
  const float* b_hh   = (const float*)d_in[5];  // [H]
  float* out = (float*)d_out;                   // [B,S,H] ++ [1,B,H] h_final

  unsigned* hbu = (unsigned*)d_ws;              // 2 tagged h slots

  dim3 g1(512, 4);
  xproj_kernel<<<g1, 256, 0, stream>>>(inputs, w_ih, b_ih, b_hh, out);
  init_kernel<<<128, 256, 0, stream>>>(hbu);
  recur_kernel<<<256, 512, 0, stream>>>(w_hh, h0, out, hbu);
}